// Round 5
// baseline (351.265 us; speedup 1.0000x reference)
//
#include <hip/hip_runtime.h>

typedef __attribute__((ext_vector_type(8))) short short8;
typedef __attribute__((ext_vector_type(4))) float f32x4;
typedef unsigned short u16;
typedef unsigned int u32;

#define MFMA_BF16(a, b, c) __builtin_amdgcn_mfma_f32_16x16x32_bf16((a), (b), (c), 0, 0, 0)

constexpr int D = 1024;
constexpr int L = 2048;
constexpr int NHEAD = 16;
constexpr int HD = 64;
// fold softmax scale (1/8) and log2(e) into q at projection time
constexpr float QLAMBDA = 0.125f * 1.44269504088896340736f;

__device__ __forceinline__ u16 f2bf(float f) {
  unsigned u = __builtin_bit_cast(unsigned, f);
  u = (u + 0x7fffu + ((u >> 16) & 1u)) >> 16;
  return (u16)u;
}

__device__ __forceinline__ short8 cvt8(f32x4 lo, f32x4 hi) {
  short8 r;
  r[0] = (short)f2bf(lo[0]); r[1] = (short)f2bf(lo[1]);
  r[2] = (short)f2bf(lo[2]); r[3] = (short)f2bf(lo[3]);
  r[4] = (short)f2bf(hi[0]); r[5] = (short)f2bf(hi[1]);
  r[6] = (short)f2bf(hi[2]); r[7] = (short)f2bf(hi[3]);
  return r;
}

// async global->LDS, 16B per lane. dst must be wave-uniform; per-lane global src.
__device__ __forceinline__ void gload16(const u16* src, u16* dst) {
  __builtin_amdgcn_global_load_lds(
      (const __attribute__((address_space(1))) u32*)(src),
      (__attribute__((address_space(3))) u32*)(dst), 16, 0, 0);
}

// ---------- weight transpose + convert: W[k][n] f32 -> WT[n][k] bf16 ----------
__global__ __launch_bounds__(256) void wt_trans_kernel(const float* W0, const float* W1,
                                                       const float* W2, const float* W3,
                                                       u16* out) {
  const float* W = blockIdx.z == 0 ? W0 : blockIdx.z == 1 ? W1 : blockIdx.z == 2 ? W2 : W3;
  u16* o = out + (size_t)blockIdx.z * D * D;
  __shared__ float t[32][33];
  int x = threadIdx.x & 31, y = threadIdx.x >> 5;
  int k0 = blockIdx.x * 32, n0 = blockIdx.y * 32;
#pragma unroll
  for (int i = 0; i < 4; i++) {
    int ky = y * 4 + i;
    t[ky][x] = W[(size_t)(k0 + ky) * D + n0 + x];
  }
  __syncthreads();
#pragma unroll
  for (int i = 0; i < 4; i++) {
    int ny = y * 4 + i;
    o[(size_t)(n0 + ny) * D + k0 + x] = f2bf(t[x][ny]);
  }
}

// ---------- RoPE tables ----------
__global__ __launch_bounds__(256) void rope_tab_kernel(float* ct, float* st) {
  int t = blockIdx.x * 256 + threadIdx.x;  // L*32 = 65536
  int i = t & 31, pos = t >> 5;
  float invf = powf(10000.0f, -(float)i / 32.0f);
  float ang = (float)pos * invf;
  ct[t] = cosf(ang);
  st[t] = sinf(ang);
}

// ---------- convert X (Q,K,V inputs) f32 -> bf16 ----------
__global__ __launch_bounds__(256) void cvt_x_kernel(const float* Q, const float* K,
                                                    const float* V, u16* xb) {
  const float* src = blockIdx.y == 0 ? Q : blockIdx.y == 1 ? K : V;
  u16* dst = xb + (size_t)blockIdx.y * 4096 * D;
  int t = blockIdx.x * 256 + threadIdx.x;  // 524288 threads, 8 elems each
  const float* p = src + (size_t)t * 8;
  f32x4 lo = *(const f32x4*)p;
  f32x4 hi = *(const f32x4*)(p + 4);
  *(short8*)(dst + (size_t)t * 8) = cvt8(lo, hi);
}

// ======== staged GEMM core (128x128 tile, BK=32, LDS dbuf, gload_lds) ========

// ---------- fused QKV projection GEMM + bias + RoPE epilogue ----------
__global__ __launch_bounds__(256, 3) void proj_gemm_staged(
    const u16* xb, const u16* wT,
    const float* bq, const float* bk, const float* bv,
    const float* ct, const float* st,
    u16* qo, u16* ko, u16* vT) {
  int i = blockIdx.x;  // 768 blocks, bijective XCD swizzle (768%8==0)
  int swz = (i & 7) * 96 + (i >> 3);
  int z = swz >> 8;
  int bx = swz & 7;
  int by = (swz >> 3) & 31;

  const u16* A = xb + (size_t)z * 4096 * D;
  const u16* W = wT + (size_t)z * D * D;
  const float* bias = z == 0 ? bq : z == 1 ? bk : bv;

  int w = threadIdx.x >> 6, lane = threadIdx.x & 63;
  int r = lane & 15, c = lane >> 4;
  int wr = w >> 1, wc = w & 1;
  int m0 = by * 128 + wr * 64;
  int n0 = bx * 128 + wc * 64;

  __shared__ __align__(16) u16 lsA[2][4096];
  __shared__ __align__(16) u16 lsB[2][4096];

  const u16* aSrc[2];
  const u16* bSrc[2];
  int dstOff[2];
#pragma unroll
  for (int i2 = 0; i2 < 2; i2++) {
    int q0 = i2 * 256 + w * 64;
    int qq = q0 + lane;
    int t = qq >> 2;
    int gch = (qq & 3) ^ ((t >> 1) & 3);
    aSrc[i2] = A + (size_t)(by * 128 + t) * D + gch * 8;
    bSrc[i2] = W + (size_t)(bx * 128 + t) * D + gch * 8;
    dstOff[i2] = q0 * 8;
  }

  int aOff[4], bOff[4];
#pragma unroll
  for (int mi = 0; mi < 4; mi++) {
    int rowA = wr * 64 + mi * 16 + r;
    aOff[mi] = rowA * 32 + ((c ^ ((rowA >> 1) & 3)) << 3);
    int rowB = wc * 64 + mi * 16 + r;
    bOff[mi] = rowB * 32 + ((c ^ ((rowB >> 1) & 3)) << 3);
  }

  f32x4 acc[4][4];
#pragma unroll
  for (int mi = 0; mi < 4; mi++)
#pragma unroll
    for (int ni = 0; ni < 4; ni++) acc[mi][ni] = f32x4{0.f, 0.f, 0.f, 0.f};

#pragma unroll
  for (int i2 = 0; i2 < 2; i2++) {
    gload16(aSrc[i2], &lsA[0][dstOff[i2]]);
    gload16(bSrc[i2], &lsB[0][dstOff[i2]]);
  }

  auto compute = [&](const u16* pa, const u16* pb) {
    short8 af[4], bf[4];
#pragma unroll
    for (int mi = 0; mi < 4; mi++) af[mi] = *(const short8*)(pa + aOff[mi]);
#pragma unroll
    for (int ni = 0; ni < 4; ni++) bf[ni] = *(const short8*)(pb + bOff[ni]);
#pragma unroll
    for (int mi = 0; mi < 4; mi++)
#pragma unroll
      for (int ni = 0; ni < 4; ni++)
        acc[mi][ni] = MFMA_BF16(af[mi], bf[ni], acc[mi][ni]);
  };

  for (int kt = 0; kt < 31; kt++) {
    int cur = kt & 1;
    __syncthreads();
#pragma unroll
    for (int i2 = 0; i2 < 2; i2++) {
      gload16(aSrc[i2] + (kt + 1) * 32, &lsA[cur ^ 1][dstOff[i2]]);
      gload16(bSrc[i2] + (kt + 1) * 32, &lsB[cur ^ 1][dstOff[i2]]);
    }
    compute(lsA[cur], lsB[cur]);
  }
  __syncthreads();
  compute(lsA[1], lsB[1]);

  int h = n0 >> 6;
#pragma unroll
  for (int mi = 0; mi < 4; mi++) {
#pragma unroll
    for (int j = 0; j < 4; j++) {
      int grow = m0 + mi * 16 + c * 4 + j;
      int b = grow >> 11, ll = grow & 2047;
      if (z < 2) {
        u16* o = (z == 0) ? qo : ko;
        float lam = (z == 0) ? QLAMBDA : 1.0f;
        size_t dst = ((size_t)(b * NHEAD + h) * L + ll) * HD;
#pragma unroll
        for (int ni = 0; ni < 2; ni++) {
          int d = ni * 16 + r;  // 0..31
          float x1 = acc[mi][ni][j] + bias[n0 + d];
          float x2 = acc[mi][ni + 2][j] + bias[n0 + 32 + d];
          float cs = ct[ll * 32 + d], sn = st[ll * 32 + d];
          o[dst + d]      = f2bf((x1 * cs - x2 * sn) * lam);
          o[dst + d + 32] = f2bf((x2 * cs + x1 * sn) * lam);
        }
      } else {
#pragma unroll
        for (int ni = 0; ni < 4; ni++) {
          int d = ni * 16 + r;
          float val = acc[mi][ni][j] + bias[n0 + d];
          vT[((size_t)(b * NHEAD + h) * HD + d) * L + ll] = f2bf(val);
        }
      }
    }
  }
}

// ---------- fallback projection (f32 A direct from global), if ws too small ----------
__global__ __launch_bounds__(256) void proj_gemm_f32(
    const float* Qf, const float* Kf, const float* Vf, const u16* wT,
    const float* bq, const float* bk, const float* bv,
    const float* ct, const float* st,
    u16* qo, u16* ko, u16* vT) {
  int i = blockIdx.x;
  int swz = (i & 7) * 96 + (i >> 3);
  int z = swz >> 8;
  int bx = swz & 7;
  int by = (swz >> 3) & 31;

  const u16* W = wT + (size_t)z * D * D;
  const float* bias = z == 0 ? bq : z == 1 ? bk : bv;

  int w = threadIdx.x >> 6, lane = threadIdx.x & 63;
  int r = lane & 15, c = lane >> 4;
  int wr = w >> 1, wc = w & 1;
  int m0 = by * 128 + wr * 64;
  int n0 = bx * 128 + wc * 64;

  const float* Af = z == 0 ? Qf : z == 1 ? Kf : Vf;
  const float* a0f = Af + (size_t)(m0 + r) * D + c * 8;
  const u16* b0 = W + (size_t)(n0 + r) * D + c * 8;

  f32x4 acc[4][4];
#pragma unroll
  for (int mi = 0; mi < 4; mi++)
#pragma unroll
    for (int ni = 0; ni < 4; ni++) acc[mi][ni] = f32x4{0.f, 0.f, 0.f, 0.f};

  for (int kk = 0; kk < D; kk += 32) {
    short8 af[4], bf[4];
#pragma unroll
    for (int mi = 0; mi < 4; mi++) {
      const float* ap = a0f + (size_t)mi * 16 * D;
      af[mi] = cvt8(*(const f32x4*)ap, *(const f32x4*)(ap + 4));
    }
#pragma unroll
    for (int ni = 0; ni < 4; ni++) bf[ni] = *(const short8*)(b0 + (size_t)ni * 16 * D);
#pragma unroll
    for (int mi = 0; mi < 4; mi++)
#pragma unroll
      for (int ni = 0; ni < 4; ni++)
        acc[mi][ni] = MFMA_BF16(af[mi], bf[ni], acc[mi][ni]);
    a0f += 32;
    b0 += 32;
  }

  int h = n0 >> 6;
#pragma unroll
  for (int mi = 0; mi < 4; mi++) {
#pragma unroll
    for (int j = 0; j < 4; j++) {
      int grow = m0 + mi * 16 + c * 4 + j;
      int b = grow >> 11, ll = grow & 2047;
      if (z < 2) {
        u16* o = (z == 0) ? qo : ko;
        float lam = (z == 0) ? QLAMBDA : 1.0f;
        size_t dst = ((size_t)(b * NHEAD + h) * L + ll) * HD;
#pragma unroll
        for (int ni = 0; ni < 2; ni++) {
          int d = ni * 16 + r;
          float x1 = acc[mi][ni][j] + bias[n0 + d];
          float x2 = acc[mi][ni + 2][j] + bias[n0 + 32 + d];
          float cs = ct[ll * 32 + d], sn = st[ll * 32 + d];
          o[dst + d]      = f2bf((x1 * cs - x2 * sn) * lam);
          o[dst + d + 32] = f2bf((x2 * cs + x1 * sn) * lam);
        }
      } else {
#pragma unroll
        for (int ni = 0; ni < 4; ni++) {
          int d = ni * 16 + r;
          float val = acc[mi][ni][j] + bias[n0 + d];
          vT[((size_t)(b * NHEAD + h) * HD + d) * L + ll] = f2bf(val);
        }
      }
    }
  }
}

// ---------- causal flash attention, fine-grained ----------
// 2048 blocks x 128 threads (2 waves). Block = (bh, 32-row q-tile), KVBLK=64,
// K/V direct from global (L2-resident per XCD), fixed-shift softmax (no max
// tracking -- scores bounded), row-sum via ones-MFMA. No barriers.
__global__ __launch_bounds__(128) void attn_kernel(const u16* qg, const u16* kg,
                                                   const u16* vg, u16* O) {
  int i = blockIdx.x;
  int xcd = i & 7, j = i >> 3;        // j in [0,256)
  int bh = xcd * 4 + (j & 3);         // 4 heads per XCD -> K/V L2 affinity
  int qt = 63 - (j >> 2);             // 32-row tile, heavy-first

  int w = threadIdx.x >> 6, lane = threadIdx.x & 63;
  int r = lane & 15, c = lane >> 4;
  int qb = qt * 32 + w * 16;

  const u16* qp = qg + ((size_t)bh * L + qb) * HD;
  const u16* kp = kg + (size_t)bh * L * HD;
  const u16* vp = vg + (size_t)bh * HD * L;

  // per-wave P bounce; stride 72 u16 (144B) puts b128 reads at the bank floor
  __shared__ __align__(16) u16 plds[2][16][72];

  short8 aq0 = *(const short8*)(qp + r * HD + c * 8);
  short8 aq1 = *(const short8*)(qp + r * HD + 32 + c * 8);

  const short one_bf = (short)0x3F80;
  short8 ones = {one_bf, one_bf, one_bf, one_bf, one_bf, one_bf, one_bf, one_bf};

  f32x4 o[4];
  f32x4 sac = f32x4{0.f, 0.f, 0.f, 0.f};
#pragma unroll
  for (int n = 0; n < 4; n++) o[n] = f32x4{0.f, 0.f, 0.f, 0.f};

  int nkt = (qt >> 1) + 1;
  for (int kt = 0; kt < nkt; kt++) {
    int kbase = kt * 64;

    f32x4 S[4];
#pragma unroll
    for (int ks = 0; ks < 4; ks++) {
      const u16* krow = kp + (size_t)(kbase + ks * 16 + r) * HD + c * 8;
      short8 kf0 = *(const short8*)(krow);
      short8 kf1 = *(const short8*)(krow + 32);
      S[ks] = f32x4{0.f, 0.f, 0.f, 0.f};
      S[ks] = MFMA_BF16(aq0, kf0, S[ks]);
      S[ks] = MFMA_BF16(aq1, kf1, S[ks]);
    }

    bool edge = (kbase + 63) > qb;
#pragma unroll
    for (int j4 = 0; j4 < 4; j4++) {
      float p0 = exp2f(S[0][j4]);
      float p1 = exp2f(S[1][j4]);
      float p2 = exp2f(S[2][j4]);
      float p3 = exp2f(S[3][j4]);
      if (edge) {
        int qrow = qb + c * 4 + j4;
        if (kbase + r > qrow) p0 = 0.f;
        if (kbase + 16 + r > qrow) p1 = 0.f;
        if (kbase + 32 + r > qrow) p2 = 0.f;
        if (kbase + 48 + r > qrow) p3 = 0.f;
      }
      int prow = c * 4 + j4;
      plds[w][prow][r]      = f2bf(p0);
      plds[w][prow][16 + r] = f2bf(p1);
      plds[w][prow][32 + r] = f2bf(p2);
      plds[w][prow][48 + r] = f2bf(p3);
    }

    short8 pa0 = *(const short8*)&plds[w][r][c * 8];
    short8 pa1 = *(const short8*)&plds[w][r][32 + c * 8];
    sac = MFMA_BF16(pa0, ones, sac);
    sac = MFMA_BF16(pa1, ones, sac);
#pragma unroll
    for (int n = 0; n < 4; n++) {
      const u16* vrow = vp + (size_t)(n * 16 + r) * L + kbase + c * 8;
      short8 vf0 = *(const short8*)(vrow);
      short8 vf1 = *(const short8*)(vrow + 32);
      o[n] = MFMA_BF16(pa0, vf0, o[n]);
      o[n] = MFMA_BF16(pa1, vf1, o[n]);
    }
  }

  int b = bh >> 4, h = bh & 15;
#pragma unroll
  for (int j4 = 0; j4 < 4; j4++) {
    int qrow = qb + c * 4 + j4;
    float inv = 1.0f / sac[j4];
#pragma unroll
    for (int n = 0; n < 4; n++) {
      O[((size_t)(b * L + qrow)) * D + h * HD + n * 16 + r] = f2bf(o[n][j4] * inv);
    }
  }
}

// ---------- output projection (staged), f32 out + bias ----------
__global__ __launch_bounds__(256, 3) void oproj_gemm_staged(const u16* Ag, const u16* wT,
                                                            const float* bias, float* out) {
  int i = blockIdx.x;  // 256 blocks
  int swz = (i & 7) * 32 + (i >> 3);
  int bx = swz & 7, by = swz >> 3;

  int w = threadIdx.x >> 6, lane = threadIdx.x & 63;
  int r = lane & 15, c = lane >> 4;
  int wr = w >> 1, wc = w & 1;
  int m0 = by * 128 + wr * 64;
  int n0 = bx * 128 + wc * 64;

  __shared__ __align__(16) u16 lsA[2][4096];
  __shared__ __align__(16) u16 lsB[2][4096];

  const u16* aSrc[2];
  const u16* bSrc[2];
  int dstOff[2];
#pragma unroll
  for (int i2 = 0; i2 < 2; i2++) {
    int q0 = i2 * 256 + w * 64;
    int qq = q0 + lane;
    int t = qq >> 2;
    int gch = (qq & 3) ^ ((t >> 1) & 3);
    aSrc[i2] = Ag + (size_t)(by * 128 + t) * D + gch * 8;
    bSrc[i2] = wT + (size_t)(bx * 128 + t) * D + gch * 8;
    dstOff[i2] = q0 * 8;
  }

  int aOff[4], bOff[4];
#pragma unroll
  for (int mi = 0; mi < 4; mi++) {
    int rowA = wr * 64 + mi * 16 + r;
    aOff[mi] = rowA * 32 + ((c ^ ((rowA >> 1) & 3)) << 3);
    int rowB = wc * 64 + mi * 16 + r;
    bOff[mi] = rowB * 32 + ((c ^ ((rowB >> 1) & 3)) << 3);
  }

  f32x4 acc[4][4];
#pragma unroll
  for (int mi = 0; mi < 4; mi++)
#pragma unroll
    for (int ni = 0; ni < 4; ni++) acc[mi][ni] = f32x4{0.f, 0.f, 0.f, 0.f};

#pragma unroll
  for (int i2 = 0; i2 < 2; i2++) {
    gload16(aSrc[i2], &lsA[0][dstOff[i2]]);
    gload16(bSrc[i2], &lsB[0][dstOff[i2]]);
  }

  auto compute = [&](const u16* pa, const u16* pb) {
    short8 af[4], bf[4];
#pragma unroll
    for (int mi = 0; mi < 4; mi++) af[mi] = *(const short8*)(pa + aOff[mi]);
#pragma unroll
    for (int ni = 0; ni < 4; ni++) bf[ni] = *(const short8*)(pb + bOff[ni]);
#pragma unroll
    for (int mi = 0; mi < 4; mi++)
#pragma unroll
      for (int ni = 0; ni < 4; ni++)
        acc[mi][ni] = MFMA_BF16(af[mi], bf[ni], acc[mi][ni]);
  };

  for (int kt = 0; kt < 31; kt++) {
    int cur = kt & 1;
    __syncthreads();
#pragma unroll
    for (int i2 = 0; i2 < 2; i2++) {
      gload16(aSrc[i2] + (kt + 1) * 32, &lsA[cur ^ 1][dstOff[i2]]);
      gload16(bSrc[i2] + (kt + 1) * 32, &lsB[cur ^ 1][dstOff[i2]]);
    }
    compute(lsA[cur], lsB[cur]);
  }
  __syncthreads();
  compute(lsA[1], lsB[1]);

#pragma unroll
  for (int mi = 0; mi < 4; mi++)
#pragma unroll
    for (int j = 0; j < 4; j++) {
      int grow = m0 + mi * 16 + c * 4 + j;
#pragma unroll
      for (int ni = 0; ni < 4; ni++) {
        int gcol = n0 + ni * 16 + r;
        out[(size_t)grow * D + gcol] = acc[mi][ni][j] + bias[gcol];
      }
    }
}

extern "C" void kernel_launch(void* const* d_in, const int* in_sizes, int n_in,
                              void* d_out, int out_size, void* d_ws, size_t ws_size,
                              hipStream_t stream) {
  const float* Q = (const float*)d_in[0];
  const float* K = (const float*)d_in[1];
  const float* V = (const float*)d_in[2];
  const float* Wq = (const float*)d_in[3];
  const float* Wk = (const float*)d_in[4];
  const float* Wv = (const float*)d_in[5];
  const float* Wo = (const float*)d_in[6];
  const float* bq = (const float*)d_in[7];
  const float* bk = (const float*)d_in[8];
  const float* bv = (const float*)d_in[9];
  const float* bo = (const float*)d_in[10];
  float* out = (float*)d_out;

  char* ws = (char*)d_ws;
  u16* wT = (u16*)(ws);
  u16* woT = wT + (size_t)3 * 1024 * 1024;
  float* ct = (float*)(ws + 8388608);
  float* st = (float*)(ws + 8650752);
  u16* qbuf = (u16*)(ws + 8912896);
  u16* kbuf = (u16*)(ws + 17301504);
  u16* vbuf = (u16*)(ws + 25690112);
  u16* obuf = (u16*)(ws + 34078720);
  u16* xb = (u16*)(ws + 42467328);

  wt_trans_kernel<<<dim3(32, 32, 4), 256, 0, stream>>>(Wq, Wk, Wv, Wo, wT);
  rope_tab_kernel<<<dim3(256), 256, 0, stream>>>(ct, st);

  if (ws_size >= (size_t)67633152) {
    cvt_x_kernel<<<dim3(2048, 3), 256, 0, stream>>>(Q, K, V, xb);
    proj_gemm_staged<<<dim3(768), 256, 0, stream>>>(xb, wT, bq, bk, bv, ct, st,
                                                    qbuf, kbuf, vbuf);
  } else {
    proj_gemm_f32<<<dim3(768), 256, 0, stream>>>(Q, K, V, wT, bq, bk, bv, ct, st,
                                                 qbuf, kbuf, vbuf);
  }
  attn_kernel<<<dim3(2048), 128, 0, stream>>>(qbuf, kbuf, vbuf, obuf);
  oproj_gemm_staged<<<dim3(256), 256, 0, stream>>>(obuf, woT, bo, out);
}

// Round 6
// 264.909 us; speedup vs baseline: 1.3260x; 1.3260x over previous
//
#include <hip/hip_runtime.h>

typedef __attribute__((ext_vector_type(8))) short short8;
typedef __attribute__((ext_vector_type(4))) float f32x4;
typedef unsigned short u16;
typedef unsigned int u32;

#define MFMA_BF16(a, b, c) __builtin_amdgcn_mfma_f32_16x16x32_bf16((a), (b), (c), 0, 0, 0)

constexpr int D = 1024;
constexpr int L = 2048;
constexpr int NHEAD = 16;
constexpr int HD = 64;
// fold softmax scale (1/8) and log2(e) into q at projection time
constexpr float QLAMBDA = 0.125f * 1.44269504088896340736f;

__device__ __forceinline__ u16 f2bf(float f) {
  unsigned u = __builtin_bit_cast(unsigned, f);
  u = (u + 0x7fffu + ((u >> 16) & 1u)) >> 16;
  return (u16)u;
}

__device__ __forceinline__ short8 cvt8(f32x4 lo, f32x4 hi) {
  short8 r;
  r[0] = (short)f2bf(lo[0]); r[1] = (short)f2bf(lo[1]);
  r[2] = (short)f2bf(lo[2]); r[3] = (short)f2bf(lo[3]);
  r[4] = (short)f2bf(hi[0]); r[5] = (short)f2bf(hi[1]);
  r[6] = (short)f2bf(hi[2]); r[7] = (short)f2bf(hi[3]);
  return r;
}

// async global->LDS, 16B per lane. dst must be wave-uniform; per-lane global src.
__device__ __forceinline__ void gload16(const u16* src, u16* dst) {
  __builtin_amdgcn_global_load_lds(
      (const __attribute__((address_space(1))) u32*)(src),
      (__attribute__((address_space(3))) u32*)(dst), 16, 0, 0);
}

// ---------- weight transpose + convert: W[k][n] f32 -> WT[n][k] bf16 ----------
__global__ __launch_bounds__(256) void wt_trans_kernel(const float* W0, const float* W1,
                                                       const float* W2, const float* W3,
                                                       u16* out) {
  const float* W = blockIdx.z == 0 ? W0 : blockIdx.z == 1 ? W1 : blockIdx.z == 2 ? W2 : W3;
  u16* o = out + (size_t)blockIdx.z * D * D;
  __shared__ float t[32][33];
  int x = threadIdx.x & 31, y = threadIdx.x >> 5;
  int k0 = blockIdx.x * 32, n0 = blockIdx.y * 32;
#pragma unroll
  for (int i = 0; i < 4; i++) {
    int ky = y * 4 + i;
    t[ky][x] = W[(size_t)(k0 + ky) * D + n0 + x];
  }
  __syncthreads();
#pragma unroll
  for (int i = 0; i < 4; i++) {
    int ny = y * 4 + i;
    o[(size_t)(n0 + ny) * D + k0 + x] = f2bf(t[x][ny]);
  }
}

// ---------- RoPE tables ----------
__global__ __launch_bounds__(256) void rope_tab_kernel(float* ct, float* st) {
  int t = blockIdx.x * 256 + threadIdx.x;  // L*32 = 65536
  int i = t & 31, pos = t >> 5;
  float invf = powf(10000.0f, -(float)i / 32.0f);
  float ang = (float)pos * invf;
  ct[t] = cosf(ang);
  st[t] = sinf(ang);
}

// ---------- convert X (Q,K,V inputs) f32 -> bf16 ----------
__global__ __launch_bounds__(256) void cvt_x_kernel(const float* Q, const float* K,
                                                    const float* V, u16* xb) {
  const float* src = blockIdx.y == 0 ? Q : blockIdx.y == 1 ? K : V;
  u16* dst = xb + (size_t)blockIdx.y * 4096 * D;
  int t = blockIdx.x * 256 + threadIdx.x;  // 524288 threads, 8 elems each
  const float* p = src + (size_t)t * 8;
  f32x4 lo = *(const f32x4*)p;
  f32x4 hi = *(const f32x4*)(p + 4);
  *(short8*)(dst + (size_t)t * 8) = cvt8(lo, hi);
}

// ======== staged GEMM core (128x128 tile, BK=32, LDS dbuf, gload_lds) ========

// ---------- fused QKV projection GEMM + bias + RoPE epilogue ----------
__global__ __launch_bounds__(256, 3) void proj_gemm_staged(
    const u16* xb, const u16* wT,
    const float* bq, const float* bk, const float* bv,
    const float* ct, const float* st,
    u16* qo, u16* ko, u16* vT) {
  int i = blockIdx.x;  // 768 blocks, bijective XCD swizzle (768%8==0)
  int swz = (i & 7) * 96 + (i >> 3);
  int z = swz >> 8;
  int bx = swz & 7;
  int by = (swz >> 3) & 31;

  const u16* A = xb + (size_t)z * 4096 * D;
  const u16* W = wT + (size_t)z * D * D;
  const float* bias = z == 0 ? bq : z == 1 ? bk : bv;

  int w = threadIdx.x >> 6, lane = threadIdx.x & 63;
  int r = lane & 15, c = lane >> 4;
  int wr = w >> 1, wc = w & 1;
  int m0 = by * 128 + wr * 64;
  int n0 = bx * 128 + wc * 64;

  __shared__ __align__(16) u16 lsA[2][4096];
  __shared__ __align__(16) u16 lsB[2][4096];

  const u16* aSrc[2];
  const u16* bSrc[2];
  int dstOff[2];
#pragma unroll
  for (int i2 = 0; i2 < 2; i2++) {
    int q0 = i2 * 256 + w * 64;
    int qq = q0 + lane;
    int t = qq >> 2;
    int gch = (qq & 3) ^ ((t >> 1) & 3);
    aSrc[i2] = A + (size_t)(by * 128 + t) * D + gch * 8;
    bSrc[i2] = W + (size_t)(bx * 128 + t) * D + gch * 8;
    dstOff[i2] = q0 * 8;
  }

  int aOff[4], bOff[4];
#pragma unroll
  for (int mi = 0; mi < 4; mi++) {
    int rowA = wr * 64 + mi * 16 + r;
    aOff[mi] = rowA * 32 + ((c ^ ((rowA >> 1) & 3)) << 3);
    int rowB = wc * 64 + mi * 16 + r;
    bOff[mi] = rowB * 32 + ((c ^ ((rowB >> 1) & 3)) << 3);
  }

  f32x4 acc[4][4];
#pragma unroll
  for (int mi = 0; mi < 4; mi++)
#pragma unroll
    for (int ni = 0; ni < 4; ni++) acc[mi][ni] = f32x4{0.f, 0.f, 0.f, 0.f};

#pragma unroll
  for (int i2 = 0; i2 < 2; i2++) {
    gload16(aSrc[i2], &lsA[0][dstOff[i2]]);
    gload16(bSrc[i2], &lsB[0][dstOff[i2]]);
  }

  auto compute = [&](const u16* pa, const u16* pb) {
    short8 af[4], bf[4];
#pragma unroll
    for (int mi = 0; mi < 4; mi++) af[mi] = *(const short8*)(pa + aOff[mi]);
#pragma unroll
    for (int ni = 0; ni < 4; ni++) bf[ni] = *(const short8*)(pb + bOff[ni]);
#pragma unroll
    for (int mi = 0; mi < 4; mi++)
#pragma unroll
      for (int ni = 0; ni < 4; ni++)
        acc[mi][ni] = MFMA_BF16(af[mi], bf[ni], acc[mi][ni]);
  };

  for (int kt = 0; kt < 31; kt++) {
    int cur = kt & 1;
    __syncthreads();
#pragma unroll
    for (int i2 = 0; i2 < 2; i2++) {
      gload16(aSrc[i2] + (kt + 1) * 32, &lsA[cur ^ 1][dstOff[i2]]);
      gload16(bSrc[i2] + (kt + 1) * 32, &lsB[cur ^ 1][dstOff[i2]]);
    }
    compute(lsA[cur], lsB[cur]);
  }
  __syncthreads();
  compute(lsA[1], lsB[1]);

  int h = n0 >> 6;
#pragma unroll
  for (int mi = 0; mi < 4; mi++) {
#pragma unroll
    for (int j = 0; j < 4; j++) {
      int grow = m0 + mi * 16 + c * 4 + j;
      int b = grow >> 11, ll = grow & 2047;
      if (z < 2) {
        u16* o = (z == 0) ? qo : ko;
        float lam = (z == 0) ? QLAMBDA : 1.0f;
        size_t dst = ((size_t)(b * NHEAD + h) * L + ll) * HD;
#pragma unroll
        for (int ni = 0; ni < 2; ni++) {
          int d = ni * 16 + r;  // 0..31
          float x1 = acc[mi][ni][j] + bias[n0 + d];
          float x2 = acc[mi][ni + 2][j] + bias[n0 + 32 + d];
          float cs = ct[ll * 32 + d], sn = st[ll * 32 + d];
          o[dst + d]      = f2bf((x1 * cs - x2 * sn) * lam);
          o[dst + d + 32] = f2bf((x2 * cs + x1 * sn) * lam);
        }
      } else {
#pragma unroll
        for (int ni = 0; ni < 4; ni++) {
          int d = ni * 16 + r;
          float val = acc[mi][ni][j] + bias[n0 + d];
          vT[((size_t)(b * NHEAD + h) * HD + d) * L + ll] = f2bf(val);
        }
      }
    }
  }
}

// ---------- fallback projection (f32 A direct from global), if ws too small ----------
__global__ __launch_bounds__(256) void proj_gemm_f32(
    const float* Qf, const float* Kf, const float* Vf, const u16* wT,
    const float* bq, const float* bk, const float* bv,
    const float* ct, const float* st,
    u16* qo, u16* ko, u16* vT) {
  int i = blockIdx.x;
  int swz = (i & 7) * 96 + (i >> 3);
  int z = swz >> 8;
  int bx = swz & 7;
  int by = (swz >> 3) & 31;

  const u16* W = wT + (size_t)z * D * D;
  const float* bias = z == 0 ? bq : z == 1 ? bk : bv;

  int w = threadIdx.x >> 6, lane = threadIdx.x & 63;
  int r = lane & 15, c = lane >> 4;
  int wr = w >> 1, wc = w & 1;
  int m0 = by * 128 + wr * 64;
  int n0 = bx * 128 + wc * 64;

  const float* Af = z == 0 ? Qf : z == 1 ? Kf : Vf;
  const float* a0f = Af + (size_t)(m0 + r) * D + c * 8;
  const u16* b0 = W + (size_t)(n0 + r) * D + c * 8;

  f32x4 acc[4][4];
#pragma unroll
  for (int mi = 0; mi < 4; mi++)
#pragma unroll
    for (int ni = 0; ni < 4; ni++) acc[mi][ni] = f32x4{0.f, 0.f, 0.f, 0.f};

  for (int kk = 0; kk < D; kk += 32) {
    short8 af[4], bf[4];
#pragma unroll
    for (int mi = 0; mi < 4; mi++) {
      const float* ap = a0f + (size_t)mi * 16 * D;
      af[mi] = cvt8(*(const f32x4*)ap, *(const f32x4*)(ap + 4));
    }
#pragma unroll
    for (int ni = 0; ni < 4; ni++) bf[ni] = *(const short8*)(b0 + (size_t)ni * 16 * D);
#pragma unroll
    for (int mi = 0; mi < 4; mi++)
#pragma unroll
      for (int ni = 0; ni < 4; ni++)
        acc[mi][ni] = MFMA_BF16(af[mi], bf[ni], acc[mi][ni]);
    a0f += 32;
    b0 += 32;
  }

  int h = n0 >> 6;
#pragma unroll
  for (int mi = 0; mi < 4; mi++) {
#pragma unroll
    for (int j = 0; j < 4; j++) {
      int grow = m0 + mi * 16 + c * 4 + j;
      int b = grow >> 11, ll = grow & 2047;
      if (z < 2) {
        u16* o = (z == 0) ? qo : ko;
        float lam = (z == 0) ? QLAMBDA : 1.0f;
        size_t dst = ((size_t)(b * NHEAD + h) * L + ll) * HD;
#pragma unroll
        for (int ni = 0; ni < 2; ni++) {
          int d = ni * 16 + r;
          float x1 = acc[mi][ni][j] + bias[n0 + d];
          float x2 = acc[mi][ni + 2][j] + bias[n0 + 32 + d];
          float cs = ct[ll * 32 + d], sn = st[ll * 32 + d];
          o[dst + d]      = f2bf((x1 * cs - x2 * sn) * lam);
          o[dst + d + 32] = f2bf((x2 * cs + x1 * sn) * lam);
        }
      } else {
#pragma unroll
        for (int ni = 0; ni < 4; ni++) {
          int d = ni * 16 + r;
          float val = acc[mi][ni][j] + bias[n0 + d];
          vT[((size_t)(b * NHEAD + h) * HD + d) * L + ll] = f2bf(val);
        }
      }
    }
  }
}

// ---------- causal flash attention, pair-balanced ----------
// 512 blocks x 4 waves. Block = (head, q-tile pair (a, 31-a)) -> 33 K-tile
// computes per block, exactly uniform (scheduler-independent balance).
// K/V LDS-staged double-buffered (R3 pattern, 0 conflicts), fixed-shift
// exp2 softmax (scores bounded; q pre-scaled by 0.125*log2e), row-sum via
// ones-MFMA. One q-tile pair shares each staged K/V tile.
__global__ __launch_bounds__(256) void attn_kernel(const u16* qg, const u16* kg,
                                                   const u16* vg, u16* O) {
  int i = blockIdx.x;
  int xcd = i & 7, j = i >> 3;        // j in [0,64)
  int bh = xcd * 4 + (j & 3);         // 4 heads per XCD -> K/V L2 affinity
  int a = j >> 2;                     // pair index in [0,16)
  int qtA = a, qtB = 31 - a;          // 64-row tiles; B is the heavy one

  int w = threadIdx.x >> 6, lane = threadIdx.x & 63;
  int r = lane & 15, c = lane >> 4;
  int qbA = qtA * 64 + w * 16;
  int qbB = qtB * 64 + w * 16;

  const u16* qp = qg + (size_t)bh * L * HD;
  const u16* kp = kg + (size_t)bh * L * HD;
  const u16* vp = vg + (size_t)bh * HD * L;

  __shared__ __align__(16) u16 kls[2][4096];
  __shared__ __align__(16) u16 vls[2][4096];
  __shared__ __align__(16) u16 plds[4][16][64];

  short8 aqA0 = *(const short8*)(qp + (size_t)(qbA + r) * HD + c * 8);
  short8 aqA1 = *(const short8*)(qp + (size_t)(qbA + r) * HD + 32 + c * 8);
  short8 aqB0 = *(const short8*)(qp + (size_t)(qbB + r) * HD + c * 8);
  short8 aqB1 = *(const short8*)(qp + (size_t)(qbB + r) * HD + 32 + c * 8);

  const short one_bf = (short)0x3F80;
  short8 ones = {one_bf, one_bf, one_bf, one_bf, one_bf, one_bf, one_bf, one_bf};

  f32x4 oA[4], oB[4];
  f32x4 sacA = f32x4{0.f, 0.f, 0.f, 0.f};
  f32x4 sacB = f32x4{0.f, 0.f, 0.f, 0.f};
#pragma unroll
  for (int n = 0; n < 4; n++) {
    oA[n] = f32x4{0.f, 0.f, 0.f, 0.f};
    oB[n] = f32x4{0.f, 0.f, 0.f, 0.f};
  }

  int nkt = qtB + 1;  // = 32 - a >= 17

  // prologue: stage tile 0
#pragma unroll
  for (int rd = 0; rd < 2; rd++) {
    int q0 = (rd * 4 + w) << 6;
    int qq = q0 + lane;
    int row = qq >> 3;
    int gch = (qq & 7) ^ (row & 7);
    gload16(kp + (size_t)row * HD + gch * 8, &kls[0][q0 * 8]);
    gload16(vp + (size_t)row * L + gch * 8, &vls[0][q0 * 8]);
  }

  for (int kt = 0; kt < nkt; kt++) {
    int cur = kt & 1;
    __syncthreads();  // drains vmcnt: stage of buf[cur] complete
    if (kt + 1 < nkt) {
      int kb2 = (kt + 1) * 64;
      const u16* kp2 = kp + (size_t)kb2 * HD;
      const u16* vp2 = vp + kb2;
#pragma unroll
      for (int rd = 0; rd < 2; rd++) {
        int q0 = (rd * 4 + w) << 6;
        int qq = q0 + lane;
        int row = qq >> 3;
        int gch = (qq & 7) ^ (row & 7);
        gload16(kp2 + (size_t)row * HD + gch * 8, &kls[cur ^ 1][q0 * 8]);
        gload16(vp2 + (size_t)row * L + gch * 8, &vls[cur ^ 1][q0 * 8]);
      }
    }
    const u16* kb_ = kls[cur];
    const u16* vb_ = vls[cur];
    int kbase = kt * 64;

    auto do_tile = [&](const short8& qf0, const short8& qf1, f32x4* o, f32x4& sac,
                       int qb, bool edge) {
      f32x4 S[4];
#pragma unroll
      for (int ks = 0; ks < 4; ks++) {
        int row = ks * 16 + r;
        short8 kf0 = *(const short8*)(kb_ + row * 64 + ((c ^ (row & 7)) << 3));
        short8 kf1 = *(const short8*)(kb_ + row * 64 + (((4 + c) ^ (row & 7)) << 3));
        S[ks] = f32x4{0.f, 0.f, 0.f, 0.f};
        S[ks] = MFMA_BF16(qf0, kf0, S[ks]);
        S[ks] = MFMA_BF16(qf1, kf1, S[ks]);
      }
#pragma unroll
      for (int j4 = 0; j4 < 4; j4++) {
        float p0 = exp2f(S[0][j4]);
        float p1 = exp2f(S[1][j4]);
        float p2 = exp2f(S[2][j4]);
        float p3 = exp2f(S[3][j4]);
        if (edge) {
          int qrow = qb + c * 4 + j4;
          if (kbase + r > qrow) p0 = 0.f;
          if (kbase + 16 + r > qrow) p1 = 0.f;
          if (kbase + 32 + r > qrow) p2 = 0.f;
          if (kbase + 48 + r > qrow) p3 = 0.f;
        }
        int prow = c * 4 + j4, xr = (prow & 7) << 3;
        plds[w][prow][(r) ^ xr]      = f2bf(p0);
        plds[w][prow][(16 + r) ^ xr] = f2bf(p1);
        plds[w][prow][(32 + r) ^ xr] = f2bf(p2);
        plds[w][prow][(48 + r) ^ xr] = f2bf(p3);
      }
      int xrr = (r & 7) << 3;
      short8 pa0 = *(const short8*)&plds[w][r][(c * 8) ^ xrr];
      short8 pa1 = *(const short8*)&plds[w][r][(32 + c * 8) ^ xrr];
      sac = MFMA_BF16(pa0, ones, sac);
      sac = MFMA_BF16(pa1, ones, sac);
#pragma unroll
      for (int n = 0; n < 4; n++) {
        int row = n * 16 + r;
        short8 vf0 = *(const short8*)(vb_ + row * 64 + ((c ^ (row & 7)) << 3));
        short8 vf1 = *(const short8*)(vb_ + row * 64 + (((4 + c) ^ (row & 7)) << 3));
        o[n] = MFMA_BF16(pa0, vf0, o[n]);
        o[n] = MFMA_BF16(pa1, vf1, o[n]);
      }
    };

    // heavy tile B: active every iteration; edge only on the last
    do_tile(aqB0, aqB1, oB, sacB, qbB, kt == nkt - 1);
    // light tile A: active while kt <= a; edge at kt == a
    if (kt <= qtA) do_tile(aqA0, aqA1, oA, sacA, qbA, kt == qtA);
  }

  int b = bh >> 4, h = bh & 15;
#pragma unroll
  for (int j4 = 0; j4 < 4; j4++) {
    int qrowA = qbA + c * 4 + j4;
    int qrowB = qbB + c * 4 + j4;
    float invA = 1.0f / sacA[j4];
    float invB = 1.0f / sacB[j4];
#pragma unroll
    for (int n = 0; n < 4; n++) {
      O[((size_t)(b * L + qrowA)) * D + h * HD + n * 16 + r] = f2bf(oA[n][j4] * invA);
      O[((size_t)(b * L + qrowB)) * D + h * HD + n * 16 + r] = f2bf(oB[n][j4] * invB);
    }
  }
}

// ---------- output projection (staged), f32 out + bias ----------
__global__ __launch_bounds__(256, 3) void oproj_gemm_staged(const u16* Ag, const u16* wT,
                                                            const float* bias, float* out) {
  int i = blockIdx.x;  // 256 blocks
  int swz = (i & 7) * 32 + (i >> 3);
  int bx = swz & 7, by = swz >> 3;

  int w = threadIdx.x >> 6, lane = threadIdx.x & 63;
  int r = lane & 15, c = lane >> 4;
  int wr = w >> 1, wc = w & 1;
  int m0 = by * 128 + wr * 64;
  int n0 = bx * 128 + wc * 64;

  __shared__ __align__(16) u16 lsA[2][4096];
  __shared__ __align__(16) u16 lsB[2][4096];

  const u16* aSrc[2];
  const u16* bSrc[2];
  int dstOff[2];
#pragma unroll
  for (int i2 = 0; i2 < 2; i2++) {
    int q0 = i2 * 256 + w * 64;
    int qq = q0 + lane;
    int t = qq >> 2;
    int gch = (qq & 3) ^ ((t >> 1) & 3);
    aSrc[i2] = Ag + (size_t)(by * 128 + t) * D + gch * 8;
    bSrc[i2] = wT + (size_t)(bx * 128 + t) * D + gch * 8;
    dstOff[i2] = q0 * 8;
  }

  int aOff[4], bOff[4];
#pragma unroll
  for (int mi = 0; mi < 4; mi++) {
    int rowA = wr * 64 + mi * 16 + r;
    aOff[mi] = rowA * 32 + ((c ^ ((rowA >> 1) & 3)) << 3);
    int rowB = wc * 64 + mi * 16 + r;
    bOff[mi] = rowB * 32 + ((c ^ ((rowB >> 1) & 3)) << 3);
  }

  f32x4 acc[4][4];
#pragma unroll
  for (int mi = 0; mi < 4; mi++)
#pragma unroll
    for (int ni = 0; ni < 4; ni++) acc[mi][ni] = f32x4{0.f, 0.f, 0.f, 0.f};

#pragma unroll
  for (int i2 = 0; i2 < 2; i2++) {
    gload16(aSrc[i2], &lsA[0][dstOff[i2]]);
    gload16(bSrc[i2], &lsB[0][dstOff[i2]]);
  }

  auto compute = [&](const u16* pa, const u16* pb) {
    short8 af[4], bf[4];
#pragma unroll
    for (int mi = 0; mi < 4; mi++) af[mi] = *(const short8*)(pa + aOff[mi]);
#pragma unroll
    for (int ni = 0; ni < 4; ni++) bf[ni] = *(const short8*)(pb + bOff[ni]);
#pragma unroll
    for (int mi = 0; mi < 4; mi++)
#pragma unroll
      for (int ni = 0; ni < 4; ni++)
        acc[mi][ni] = MFMA_BF16(af[mi], bf[ni], acc[mi][ni]);
  };

  for (int kt = 0; kt < 31; kt++) {
    int cur = kt & 1;
    __syncthreads();
#pragma unroll
    for (int i2 = 0; i2 < 2; i2++) {
      gload16(aSrc[i2] + (kt + 1) * 32, &lsA[cur ^ 1][dstOff[i2]]);
      gload16(bSrc[i2] + (kt + 1) * 32, &lsB[cur ^ 1][dstOff[i2]]);
    }
    compute(lsA[cur], lsB[cur]);
  }
  __syncthreads();
  compute(lsA[1], lsB[1]);

#pragma unroll
  for (int mi = 0; mi < 4; mi++)
#pragma unroll
    for (int j = 0; j < 4; j++) {
      int grow = m0 + mi * 16 + c * 4 + j;
#pragma unroll
      for (int ni = 0; ni < 4; ni++) {
        int gcol = n0 + ni * 16 + r;
        out[(size_t)grow * D + gcol] = acc[mi][ni][j] + bias[gcol];
      }
    }
}

extern "C" void kernel_launch(void* const* d_in, const int* in_sizes, int n_in,
                              void* d_out, int out_size, void* d_ws, size_t ws_size,
                              hipStream_t stream) {
  const float* Q = (const float*)d_in[0];
  const float* K = (const float*)d_in[1];
  const float* V = (const float*)d_in[2];
  const float* Wq = (const float*)d_in[3];
  const float* Wk = (const float*)d_in[4];
  const float* Wv = (const float*)d_in[5];
  const float* Wo = (const float*)d_in[6];
  const float* bq = (const float*)d_in[7];
  const float* bk = (const float*)d_in[8];
  const float* bv = (const float*)d_in[9];
  const float* bo = (const float*)d_in[10];
  float* out = (float*)d_out;

  char* ws = (char*)d_ws;
  u16* wT = (u16*)(ws);
  u16* woT = wT + (size_t)3 * 1024 * 1024;
  float* ct = (float*)(ws + 8388608);
  float* st = (float*)(ws + 8650752);
  u16* qbuf = (u16*)(ws + 8912896);
  u16* kbuf = (u16*)(ws + 17301504);
  u16* vbuf = (u16*)(ws + 25690112);
  u16* obuf = (u16*)(ws + 34078720);
  u16* xb = (u16*)(ws + 42467328);

  wt_trans_kernel<<<dim3(32, 32, 4), 256, 0, stream>>>(Wq, Wk, Wv, Wo, wT);
  rope_tab_kernel<<<dim3(256), 256, 0, stream>>>(ct, st);

  if (ws_size >= (size_t)67633152) {
    cvt_x_kernel<<<dim3(2048, 3), 256, 0, stream>>>(Q, K, V, xb);
    proj_gemm_staged<<<dim3(768), 256, 0, stream>>>(xb, wT, bq, bk, bv, ct, st,
                                                    qbuf, kbuf, vbuf);
  } else {
    proj_gemm_f32<<<dim3(768), 256, 0, stream>>>(Q, K, V, wT, bq, bk, bv, ct, st,
                                                 qbuf, kbuf, vbuf);
  }
  attn_kernel<<<dim3(512), 256, 0, stream>>>(qbuf, kbuf, vbuf, obuf);
  oproj_gemm_staged<<<dim3(256), 256, 0, stream>>>(obuf, woT, bo, out);
}